// Round 1
// baseline (378.211 us; speedup 1.0000x reference)
//
#include <hip/hip_runtime.h>
#include <hip/hip_bf16.h>
#include <stdint.h>
#include <stddef.h>

// ---------------- workspace layout (bytes) ----------------
// 0     : uint32 flag (0 = f32 inputs, 1 = bf16 inputs)
// 64    : double F[80]          (FF_FILT[t,b] = F[t*8+b], f64)
// 768   : double trI[2048*8]    (i-major trace0: trI[i*8+b])
// 131840: double s0[2048]
// 148224: double s1[2048]
#define WS_F_OFF      64
#define WS_TRACE0_OFF 768
#define WS_S0_OFF     131840
#define WS_S1_OFF     148224

// ---------------- threefry2x32 (JAX-exact, 20 rounds) ----------------
__host__ __device__ inline void tf2x32(uint32_t k0, uint32_t k1,
                                       uint32_t& x0, uint32_t& x1) {
  uint32_t ks0 = k0, ks1 = k1, ks2 = k0 ^ k1 ^ 0x1BD11BDAu;
  x0 += ks0; x1 += ks1;
#define TF_ROT(v, n) (((v) << (n)) | ((v) >> (32 - (n))))
#define TF_R(r) { x0 += x1; x1 = TF_ROT(x1, r); x1 ^= x0; }
  TF_R(13) TF_R(15) TF_R(26) TF_R(6)   x0 += ks1; x1 += ks2 + 1u;
  TF_R(17) TF_R(29) TF_R(16) TF_R(24)  x0 += ks2; x1 += ks0 + 2u;
  TF_R(13) TF_R(15) TF_R(26) TF_R(6)   x0 += ks0; x1 += ks1 + 3u;
  TF_R(17) TF_R(29) TF_R(16) TF_R(24)  x0 += ks1; x1 += ks2 + 4u;
  TF_R(13) TF_R(15) TF_R(26) TF_R(6)   x0 += ks2; x1 += ks0 + 5u;
#undef TF_R
#undef TF_ROT
}

__device__ inline double bf2d(unsigned short b) {
  return (double)__uint_as_float(((uint32_t)b) << 16);
}
__device__ inline unsigned short f2bf(float f) {  // RNE
  uint32_t u = __float_as_uint(f);
  u += 0x7FFFu + ((u >> 16) & 1u);
  return (unsigned short)(u >> 16);
}

// ---- prep: dtype flag (ballot) + F table + i-major trace0 ----
// grid 64 x 256; item idx = i*8+b; stores trI[i*8+b] (contiguous)
__global__ __launch_bounds__(256) void snn_prep_kernel(
    const void* __restrict__ X, uint8_t* __restrict__ ws) {
  __shared__ unsigned long long smask[4];
  __shared__ double sF[80];
  __shared__ int s_flag;
  const int tid = threadIdx.x;

  const uint32_t* xw = (const uint32_t*)X;
  uint32_t w = xw[tid];
  bool ok = (w == 0u || w == 0x3F800000u);
  unsigned long long m = __ballot(ok);
  if ((tid & 63) == 0) smask[tid >> 6] = m;

  if (tid < 80) {
    int tt = tid >> 3, b = tid & 7;
    const double PI = 3.14159265358979311599796346854;
    double arg = 0.5 * PI * log1p((double)tt) - 0.5 * PI * (double)b;
    arg = fmin(fmax(arg, -PI), PI);
    sF[tid] = 0.5 * (1.0 + cos(arg));
  }
  __syncthreads();
  if (tid == 0) {
    bool allbin = ((smask[0] & smask[1] & smask[2] & smask[3]) == ~0ull);
    s_flag = allbin ? 0 : 1;   // all exact {0.0f,1.0f} words -> f32 input
  }
  __syncthreads();
  const int flag = s_flag;

  if (blockIdx.x == 0) {
    if (tid == 0) *(uint32_t*)ws = (uint32_t)flag;
    if (tid < 80) ((double*)(ws + WS_F_OFF))[tid] = sF[tid];
  }

  const int idx = blockIdx.x * 256 + tid;   // 0..16383 = i*8+b
  const int i = idx >> 3, b = idx & 7;
  double acc = 0.0;
  if (flag) {
    const unsigned short* Xb = (const unsigned short*)X;
    #pragma unroll
    for (int t = 0; t < 10; ++t) acc += bf2d(Xb[i * 10 + (9 - t)]) * sF[t * 8 + b];
  } else {
    const float* Xf = (const float*)X;
    #pragma unroll
    for (int t = 0; t < 10; ++t) acc += (double)Xf[i * 10 + (9 - t)] * sF[t * 8 + b];
  }
  ((double*)(ws + WS_TRACE0_OFF))[idx] = acc;   // i-major store
}

// ---- layer: 4 waves per row (1 row/block), staged weight loads ----
// grid 2048 x 256. Each wave covers 1/4 of the row's (i,b) space.
// f32 path: the row is 4096 16B-chunks ("e"); chunk e = (i = e>>1,
// b = (e&1)*4 + j). Lane parity fixes which b-half a lane handles; the
// final scalar is a full sum over (i,b) so any lane partition is valid.
__global__ __launch_bounds__(256) void snn_layer_kernel(
    const void* __restrict__ W, const void* __restrict__ bias,
    const uint8_t* __restrict__ ws,
    int traceMode,                 // 0: full trace0 (i-major), 1: rank-1
    const double* __restrict__ sPrev,
    double* __restrict__ sOutD,    // may be null
    uint32_t key0, uint32_t key1,
    void* __restrict__ out, int pOff, int sOff)
{
  const uint32_t flag = *(const uint32_t*)ws;
  const double* F = (const double*)(ws + WS_F_OFF);
  const double* trI = (const double*)(ws + WS_TRACE0_OFF);
  const int lane = threadIdx.x & 63;
  const int wid  = threadIdx.x >> 6;          // 0..3 = quarter of row
  const int row  = blockIdx.x;

  double acc[8];
  #pragma unroll
  for (int b = 0; b < 8; ++b) acc[b] = 0.0;

  if (flag) {
    // ---- bf16 weights: 16B chunk = one full i-group (8 bf16) ----
    const uint4* Wq = (const uint4*)W + (size_t)row * 2048 + wid * 512;
    uint4 wb[8];
    #pragma unroll
    for (int s = 0; s < 8; ++s) wb[s] = Wq[s * 64 + lane];   // 8 KB/wave in flight

    if (traceMode == 0) {
      #pragma unroll
      for (int s = 0; s < 8; ++s) {
        int i = wid * 512 + s * 64 + lane;
        const double* t = trI + (size_t)i * 8;
        uint4 v = wb[s];
        acc[0] += bf2d((unsigned short)(v.x & 0xFFFFu)) * t[0];
        acc[1] += bf2d((unsigned short)(v.x >> 16))     * t[1];
        acc[2] += bf2d((unsigned short)(v.y & 0xFFFFu)) * t[2];
        acc[3] += bf2d((unsigned short)(v.y >> 16))     * t[3];
        acc[4] += bf2d((unsigned short)(v.z & 0xFFFFu)) * t[4];
        acc[5] += bf2d((unsigned short)(v.z >> 16))     * t[5];
        acc[6] += bf2d((unsigned short)(v.w & 0xFFFFu)) * t[6];
        acc[7] += bf2d((unsigned short)(v.w >> 16))     * t[7];
      }
    } else {
      double F0[8];
      #pragma unroll
      for (int b = 0; b < 8; ++b) F0[b] = F[b];
      #pragma unroll
      for (int s = 0; s < 8; ++s) {
        int i = wid * 512 + s * 64 + lane;
        double si = sPrev[i];
        uint4 v = wb[s];
        acc[0] += (bf2d((unsigned short)(v.x & 0xFFFFu)) * F0[0]) * si;
        acc[1] += (bf2d((unsigned short)(v.x >> 16))     * F0[1]) * si;
        acc[2] += (bf2d((unsigned short)(v.y & 0xFFFFu)) * F0[2]) * si;
        acc[3] += (bf2d((unsigned short)(v.y >> 16))     * F0[3]) * si;
        acc[4] += (bf2d((unsigned short)(v.z & 0xFFFFu)) * F0[4]) * si;
        acc[5] += (bf2d((unsigned short)(v.z >> 16))     * F0[5]) * si;
        acc[6] += (bf2d((unsigned short)(v.w & 0xFFFFu)) * F0[6]) * si;
        acc[7] += (bf2d((unsigned short)(v.w >> 16))     * F0[7]) * si;
      }
    }
  } else {
    // ---- f32 weights: 16B chunk = half an i-group (4 floats) ----
    const int ebase = wid * 1024;
    const float4* Wq = (const float4*)W + (size_t)row * 4096 + ebase;
    float4 wv[16];
    #pragma unroll
    for (int s = 0; s < 8; ++s) {            // 16 KB/wave in flight, coalesced
      wv[2 * s]     = Wq[s * 128 + lane];
      wv[2 * s + 1] = Wq[s * 128 + 64 + lane];
    }

    if (traceMode == 0) {
      #pragma unroll
      for (int s = 0; s < 8; ++s) {
        int e0 = ebase + s * 128 + lane;
        int e1 = e0 + 64;
        const double* t0 = trI + (size_t)e0 * 4;
        const double* t1 = trI + (size_t)e1 * 4;
        float4 a = wv[2 * s];
        float4 c = wv[2 * s + 1];
        acc[0] += (double)a.x * t0[0];
        acc[1] += (double)a.y * t0[1];
        acc[2] += (double)a.z * t0[2];
        acc[3] += (double)a.w * t0[3];
        acc[4] += (double)c.x * t1[0];
        acc[5] += (double)c.y * t1[1];
        acc[6] += (double)c.z * t1[2];
        acc[7] += (double)c.w * t1[3];
      }
    } else {
      // lane parity fixes the b-half: b = (lane&1)*4 + j
      double F0[4];
      const int p = lane & 1;
      #pragma unroll
      for (int j = 0; j < 4; ++j) F0[j] = F[p * 4 + j];
      #pragma unroll
      for (int s = 0; s < 8; ++s) {
        int e0 = ebase + s * 128 + lane;
        int e1 = e0 + 64;
        double s0v = sPrev[e0 >> 1];
        double s1v = sPrev[e1 >> 1];
        float4 a = wv[2 * s];
        float4 c = wv[2 * s + 1];
        acc[0] += ((double)a.x * F0[0]) * s0v;
        acc[1] += ((double)a.y * F0[1]) * s0v;
        acc[2] += ((double)a.z * F0[2]) * s0v;
        acc[3] += ((double)a.w * F0[3]) * s0v;
        acc[4] += ((double)c.x * F0[0]) * s1v;
        acc[5] += ((double)c.y * F0[1]) * s1v;
        acc[6] += ((double)c.z * F0[2]) * s1v;
        acc[7] += ((double)c.w * F0[3]) * s1v;
      }
    }
  }

  double r = ((acc[0] + acc[1]) + (acc[2] + acc[3])) +
             ((acc[4] + acc[5]) + (acc[6] + acc[7]));
  #pragma unroll
  for (int off = 32; off > 0; off >>= 1) r += __shfl_down(r, off, 64);

  __shared__ double sred[4];
  if (lane == 0) sred[wid] = r;
  __syncthreads();

  if (threadIdx.x == 0) {
    const int o = blockIdx.x;                 // this block's row
    double rr = (sred[0] + sred[1]) + (sred[2] + sred[3]);
    double bb = flag ? bf2d(((const unsigned short*)bias)[o])
                     : (double)((const float*)bias)[o];
    double x = rr + bb;
    double p = 1.0 / (1.0 + exp(-x));
    // JAX partitionable counter-mode uniform: element o -> block x=(0,o),
    // bits = out0 ^ out1
    uint32_t x0 = 0u, x1 = (uint32_t)o;
    tf2x32(key0, key1, x0, x1);
    uint32_t wbits = x0 ^ x1;
    float u = __uint_as_float((wbits >> 9) | 0x3F800000u) - 1.0f;
    double sp = ((double)u < p) ? 1.0 : 0.0;
    if (flag) {
      unsigned short* ob = (unsigned short*)out;
      ob[pOff + o] = f2bf((float)p);
      ob[sOff + o] = f2bf((float)sp);
    } else {
      float* of = (float*)out;
      of[pOff + o] = (float)p;
      of[sOff + o] = (float)sp;
    }
    if (sOutD) sOutD[o] = sp;
  }
}

extern "C" void kernel_launch(void* const* d_in, const int* in_sizes, int n_in,
                              void* d_out, int out_size, void* d_ws, size_t ws_size,
                              hipStream_t stream) {
  // keys: split(key(42), 3), partitionable scheme:
  // k_i = threefry2x32((0,42), x=(0,i)), new key = (out0, out1).
  uint32_t k0a = 0u, k0b = 0u;  tf2x32(0u, 42u, k0a, k0b);
  uint32_t k1a = 0u, k1b = 1u;  tf2x32(0u, 42u, k1a, k1b);
  uint32_t k2a = 0u, k2b = 2u;  tf2x32(0u, 42u, k2a, k2b);

  uint8_t* ws = (uint8_t*)d_ws;
  double* s0d = (double*)(ws + WS_S0_OFF);
  double* s1d = (double*)(ws + WS_S1_OFF);

  snn_prep_kernel<<<64, 256, 0, stream>>>(d_in[0], ws);
  // layer 0: W0=d_in[1], b0=d_in[3]; p0 -> out[4096..], s0 -> out[8192..]
  snn_layer_kernel<<<2048, 256, 0, stream>>>(d_in[1], d_in[3], ws, 0, nullptr, s0d,
                                             k0a, k0b, d_out, 4096, 8192);
  // layer 1: W1=d_in[4], b1=d_in[6]; p1 -> out[6144..], s1 -> out[10240..]
  snn_layer_kernel<<<2048, 256, 0, stream>>>(d_in[4], d_in[6], ws, 1, s0d, s1d,
                                             k1a, k1b, d_out, 6144, 10240);
  // layer 2: W2=d_in[7], b2=d_in[9]; p2 -> out[0..], s2 -> out[2048..]
  snn_layer_kernel<<<2048, 256, 0, stream>>>(d_in[7], d_in[9], ws, 1, s1d, nullptr,
                                             k2a, k2b, d_out, 0, 2048);
}